// Round 7
// baseline (820.548 us; speedup 1.0000x reference)
//
#include <hip/hip_runtime.h>
#include <hip/hip_bf16.h>

constexpr int V   = 100000;
constexpr int E   = 1600000;
constexpr int NET = 10;
constexpr int KXW = 138;              // W_xi row length (2*64+10)
constexpr int NB  = (V + 255) / 256;  // 391 blocks over nodes
constexpr float MUS = 0.1125f;        // MU / S

typedef __attribute__((ext_vector_type(8))) short short8;
typedef __attribute__((ext_vector_type(4))) float float4v;

__device__ __forceinline__ float fast_tanh(float x) {
    return 1.0f - 2.0f / (__expf(2.0f * x) + 1.0f);
}
__device__ __forceinline__ float bflo(unsigned u) { return __uint_as_float(u << 16); }
__device__ __forceinline__ float bfhi(unsigned u) { return __uint_as_float(u & 0xffff0000u); }
__device__ __forceinline__ short f2bf(float x) {
    union { __hip_bfloat16 b; short s; } u; u.b = __float2bfloat16(x); return u.s;
}

// ---------------------------------------------------------------------------
// CSR build: histogram over RAW 1-indexed X_Neis (drop id >= V)
// ---------------------------------------------------------------------------
__global__ __launch_bounds__(256) void hist_kernel(
    const int* __restrict__ xneis, int* __restrict__ count)
{
    int e = blockIdx.x * 256 + threadIdx.x;
    if (e >= E) return;
    int nr = xneis[e];
    if (nr < V) atomicAdd(&count[nr], 1);
}

__global__ __launch_bounds__(256) void scan_block_kernel(
    const int* __restrict__ count, int* __restrict__ scanned, int* __restrict__ blocksum)
{
    __shared__ int s[256];
    int tid = threadIdx.x;
    int i = blockIdx.x * 256 + tid;
    int v = (i < V) ? count[i] : 0;
    s[tid] = v; __syncthreads();
    #pragma unroll
    for (int off = 1; off < 256; off <<= 1) {
        int t = (tid >= off) ? s[tid - off] : 0;
        __syncthreads();
        s[tid] += t;
        __syncthreads();
    }
    if (i < V) scanned[i] = s[tid] - v;          // block-exclusive
    if (tid == 255) blocksum[blockIdx.x] = s[255];
}

__global__ __launch_bounds__(512) void scan_tops_kernel(
    const int* __restrict__ blocksum, int* __restrict__ tops, int* __restrict__ rowptr)
{
    __shared__ int s[512];
    int tid = threadIdx.x;
    int v = (tid < NB) ? blocksum[tid] : 0;
    s[tid] = v; __syncthreads();
    #pragma unroll
    for (int off = 1; off < 512; off <<= 1) {
        int t = (tid >= off) ? s[tid - off] : 0;
        __syncthreads();
        s[tid] += t;
        __syncthreads();
    }
    if (tid < NB) tops[tid] = s[tid] - v;        // exclusive
    if (tid == 511) rowptr[V] = s[511];          // total kept edges
}

__global__ __launch_bounds__(256) void add_offsets_kernel(
    const int* __restrict__ scanned, const int* __restrict__ tops, int* __restrict__ rowptr)
{
    int i = blockIdx.x * 256 + threadIdx.x;
    if (i < V) rowptr[i] = scanned[i] + tops[blockIdx.x];
}

// Writes eid[p] (edge id at CSR slot p) and esrc[p] (0-indexed source node).
__global__ __launch_bounds__(256) void scatter_kernel(
    const int* __restrict__ xnode, const int* __restrict__ xneis,
    const int* __restrict__ rowptr, int* __restrict__ cursor,
    int* __restrict__ eid, int* __restrict__ esrc)
{
    int e = blockIdx.x * 256 + threadIdx.x;
    if (e >= E) return;
    int nr = xneis[e];
    if (nr < V) {
        int p = rowptr[nr] + atomicAdd(&cursor[nr], 1);
        eid[p]  = e;
        esrc[p] = xnode[e] - 1;
    }
}

// ---------------------------------------------------------------------------
// Per-node bias sum: Bsum[v] = count[v] * tanh(W_rou·feat[v-1]+b)
// ---------------------------------------------------------------------------
__global__ __launch_bounds__(256) void bsum_kernel(
    const float* __restrict__ feat, const int* __restrict__ count,
    const float* __restrict__ Wrou, const float* __restrict__ brou,
    float* __restrict__ Bsum)
{
    __shared__ float Wl[512];
    __shared__ float bl[8];
    int tid = threadIdx.x;
    for (int i = tid; i < 512; i += 256) Wl[i] = Wrou[i];
    if (tid < 8) bl[tid] = brou[tid];
    __syncthreads();

    int v = blockIdx.x * 256 + tid;
    if (v >= V) return;
    int c = count[v];
    float out[8] = {0, 0, 0, 0, 0, 0, 0, 0};
    if (c > 0) {                                  // c>0 implies v >= 1
        const float4* f4 = (const float4*)(feat + (size_t)(v - 1) * 64);
        float acc[8];
        #pragma unroll
        for (int s = 0; s < 8; ++s) acc[s] = bl[s];
        #pragma unroll 4
        for (int k = 0; k < 16; ++k) {
            float4 x = f4[k];
            #pragma unroll
            for (int s = 0; s < 8; ++s) {
                const float* w = &Wl[s * 64 + k * 4];
                acc[s] += x.x * w[0] + x.y * w[1] + x.z * w[2] + x.w * w[3];
            }
        }
        float fc = (float)c;
        #pragma unroll
        for (int s = 0; s < 8; ++s) out[s] = fc * fast_tanh(acc[s]);
    }
    float4* O = (float4*)(Bsum + (size_t)v * 8);
    O[0] = make_float4(out[0], out[1], out[2], out[3]);
    O[1] = make_float4(out[4], out[5], out[6], out[7]);
}

// ---------------------------------------------------------------------------
// PQ GEMM (MFMA): PQ[v][0:64] = feat[v]·Wxi[:, 0:64]^T   (P part)
//                 PQ[v][64:128] = feat[v]·Wxi[:, 64:128]^T (Q part), bf16 out
// ---------------------------------------------------------------------------
__global__ __launch_bounds__(256) void pq_kernel(
    const float* __restrict__ feat, const float* __restrict__ Wxi,
    ushort* __restrict__ PQ)
{
    const int lane = threadIdx.x & 63, wave = threadIdx.x >> 6;
    const int quad = lane >> 4, l16 = lane & 15;

    short8 bP[4][2], bQ[4][2];
    #pragma unroll
    for (int nt = 0; nt < 4; ++nt) {
        #pragma unroll
        for (int ks = 0; ks < 2; ++ks) {
            const float* wp = Wxi + (size_t)(nt * 16 + l16) * KXW + ks * 32 + quad * 8;
            short8 p, q;
            #pragma unroll
            for (int j = 0; j < 8; ++j) { p[j] = f2bf(wp[j]); q[j] = f2bf(wp[64 + j]); }
            bP[nt][ks] = p; bQ[nt][ks] = q;
        }
    }

    int t = blockIdx.x * 4 + wave;
    if (t >= V / 16) return;
    int v0 = t * 16;

    const float* fp = feat + (size_t)(v0 + l16) * 64 + quad * 8;
    short8 a0, a1;
    #pragma unroll
    for (int j = 0; j < 8; ++j) { a0[j] = f2bf(fp[j]); a1[j] = f2bf(fp[32 + j]); }

    float4v accP[4], accQ[4];
    #pragma unroll
    for (int nt = 0; nt < 4; ++nt) {
        float4v z = {0.f, 0.f, 0.f, 0.f};
        z = __builtin_amdgcn_mfma_f32_16x16x32_bf16(a0, bP[nt][0], z, 0, 0, 0);
        z = __builtin_amdgcn_mfma_f32_16x16x32_bf16(a1, bP[nt][1], z, 0, 0, 0);
        accP[nt] = z;
        float4v w = {0.f, 0.f, 0.f, 0.f};
        w = __builtin_amdgcn_mfma_f32_16x16x32_bf16(a0, bQ[nt][0], w, 0, 0, 0);
        w = __builtin_amdgcn_mfma_f32_16x16x32_bf16(a1, bQ[nt][1], w, 0, 0, 0);
        accQ[nt] = w;
    }

    #pragma unroll
    for (int r = 0; r < 4; ++r) {
        ushort* row = PQ + (size_t)(v0 + quad * 4 + r) * 128;
        #pragma unroll
        for (int nt = 0; nt < 4; ++nt) {
            row[nt * 16 + l16]      = (ushort)f2bf(accP[nt][r]);
            row[64 + nt * 16 + l16] = (ushort)f2bf(accQ[nt][r]);
        }
    }
}

// ---------------------------------------------------------------------------
// Edge kernel, CSR-ORDERED: thread group owns CSR slot p, gathers edge
// metadata via eid[p] (broadcast 4 B loads, L3-resident), reads PQ (random,
// L3-resident), writes Acsr[p] SEQUENTIALLY (full write BW; round-6 scatter
// writes were the 2.4 TB/s cap). Plain stores: Acsr wants L3 residency for
// the step kernels (NT experiment was neutral-to-harmful).
// ---------------------------------------------------------------------------
__global__ __launch_bounds__(256) void edge_kernel(
    const int* __restrict__ eid, const int* __restrict__ xnode,
    const int* __restrict__ xneis, const int* __restrict__ etype,
    const float* __restrict__ dg, const int* __restrict__ rowptr,
    const ushort* __restrict__ PQ, const float* __restrict__ Wxi,
    const float* __restrict__ bxi, ushort* __restrict__ Acsr)
{
    __shared__ float WetB[NET * 64];
    int tid = threadIdx.x;
    for (int i = tid; i < NET * 64; i += 256) {
        int et = i >> 6, n = i & 63;
        WetB[i] = Wxi[n * KXW + 128 + et] + bxi[n];
    }
    __syncthreads();

    const int nkept = rowptr[V];
    size_t g = (size_t)blockIdx.x * 256 + tid;
    int p = (int)(g >> 4), l = (int)(g & 15);
    if (p >= nkept) return;

    int e   = eid[p];
    int src = xnode[e] - 1;
    int dst = xneis[e] - 1;
    int et  = etype[e] - 1;
    float sc = MUS / dg[e];

    uint2 pu = *(const uint2*)(PQ + (size_t)src * 128 + l * 4);
    uint2 qu = *(const uint2*)(PQ + (size_t)dst * 128 + 64 + l * 4);
    float4 wb = *(const float4*)(WetB + et * 64 + l * 4);

    float v0 = bflo(pu.x) + bflo(qu.x) + wb.x;
    float v1 = bfhi(pu.x) + bfhi(qu.x) + wb.y;
    float v2 = bflo(pu.y) + bflo(qu.y) + wb.z;
    float v3 = bfhi(pu.y) + bfhi(qu.y) + wb.w;

    ushort4 o;
    o.x = (ushort)f2bf(fast_tanh(v0) * sc);
    o.y = (ushort)f2bf(fast_tanh(v1) * sc);
    o.z = (ushort)f2bf(fast_tanh(v2) * sc);
    o.w = (ushort)f2bf(fast_tanh(v3) * sc);
    *(ushort4*)(Acsr + (size_t)p * 64 + l * 4) = o;
}

// ---------------------------------------------------------------------------
// One recurrence step, one wave per node: lane = el*8 + s; 8 edges in flight,
// butterfly-reduce over el.
// ---------------------------------------------------------------------------
__global__ __launch_bounds__(256) void step_kernel(
    const float* __restrict__ Hin, float* __restrict__ Hout,
    const ushort* __restrict__ A, const int* __restrict__ esrc,
    const int* __restrict__ rowptr, const float* __restrict__ Bsum)
{
    int v = blockIdx.x * 4 + (threadIdx.x >> 6);
    if (v >= V) return;
    int lane = threadIdx.x & 63;
    int el = lane >> 3, s = lane & 7;

    int p0 = rowptr[v], p1 = rowptr[v + 1];

    float acc = 0.0f;
    for (int p = p0 + el; p < p1; p += 8) {
        int src = esrc[p];
        const float4* H4 = (const float4*)(Hin + (size_t)src * 8);
        float4 h0 = H4[0], h1 = H4[1];
        uint4 av = *(const uint4*)(A + (size_t)p * 64 + s * 8);
        acc += bflo(av.x) * h0.x + bfhi(av.x) * h0.y
             + bflo(av.y) * h0.z + bfhi(av.y) * h0.w
             + bflo(av.z) * h1.x + bfhi(av.z) * h1.y
             + bflo(av.w) * h1.z + bfhi(av.w) * h1.w;
    }
    acc += __shfl_xor(acc, 8);
    acc += __shfl_xor(acc, 16);
    acc += __shfl_xor(acc, 32);
    if (el == 0)
        Hout[(size_t)v * 8 + s] = acc + Bsum[(size_t)v * 8 + s];
}

// ---------------------------------------------------------------------------
// Epilogue
// ---------------------------------------------------------------------------
__global__ __launch_bounds__(256) void logits_kernel(
    const float* __restrict__ H, const float* __restrict__ W1,
    const float* __restrict__ b1, float* __restrict__ logits)
{
    int v = blockIdx.x * 256 + threadIdx.x;
    if (v >= V) return;
    float4 w0 = ((const float4*)W1)[0], w1 = ((const float4*)W1)[1];
    const float4* H4 = (const float4*)(H + (size_t)v * 8);
    float4 h0 = H4[0], h1 = H4[1];
    logits[v] = b1[0]
              + h0.x * w0.x + h0.y * w0.y + h0.z * w0.z + h0.w * w0.w
              + h1.x * w1.x + h1.y * w1.y + h1.z * w1.z + h1.w * w1.w;
}

__global__ __launch_bounds__(256) void reduce_max_kernel(
    const float* __restrict__ logits, float* __restrict__ partial)
{
    float m = -INFINITY;
    for (int v = blockIdx.x * 256 + threadIdx.x; v < V; v += 256 * 256)
        m = fmaxf(m, logits[v]);
    #pragma unroll
    for (int o = 32; o > 0; o >>= 1) m = fmaxf(m, __shfl_down(m, o));
    __shared__ float sm[4];
    if ((threadIdx.x & 63) == 0) sm[threadIdx.x >> 6] = m;
    __syncthreads();
    if (threadIdx.x == 0)
        partial[blockIdx.x] = fmaxf(fmaxf(sm[0], sm[1]), fmaxf(sm[2], sm[3]));
}

__global__ __launch_bounds__(256) void final_max_kernel(
    const float* __restrict__ partial, float* __restrict__ M)
{
    float m = partial[threadIdx.x];
    #pragma unroll
    for (int o = 32; o > 0; o >>= 1) m = fmaxf(m, __shfl_down(m, o));
    __shared__ float sm[4];
    if ((threadIdx.x & 63) == 0) sm[threadIdx.x >> 6] = m;
    __syncthreads();
    if (threadIdx.x == 0) *M = fmaxf(fmaxf(sm[0], sm[1]), fmaxf(sm[2], sm[3]));
}

__global__ __launch_bounds__(256) void sum_kernel(
    const float* __restrict__ H, const float* __restrict__ logits,
    const float* __restrict__ Mp, float* __restrict__ accum)
{
    const float M = *Mp;
    float se = 0.0f;
    float sh[8] = {0, 0, 0, 0, 0, 0, 0, 0};
    for (int v = blockIdx.x * 256 + threadIdx.x; v < V; v += 256 * 256) {
        float w = __expf(logits[v] - M);
        se += w;
        const float4* H4 = (const float4*)(H + (size_t)v * 8);
        float4 h0 = H4[0], h1 = H4[1];
        sh[0] += w * h0.x; sh[1] += w * h0.y; sh[2] += w * h0.z; sh[3] += w * h0.w;
        sh[4] += w * h1.x; sh[5] += w * h1.y; sh[6] += w * h1.z; sh[7] += w * h1.w;
    }
    #pragma unroll
    for (int o = 32; o > 0; o >>= 1) {
        se += __shfl_down(se, o);
        #pragma unroll
        for (int i = 0; i < 8; ++i) sh[i] += __shfl_down(sh[i], o);
    }
    if ((threadIdx.x & 63) == 0) {
        atomicAdd(&accum[8], se);
        #pragma unroll
        for (int i = 0; i < 8; ++i) atomicAdd(&accum[i], sh[i]);
    }
}

__global__ void final_kernel(const float* __restrict__ accum, float* __restrict__ out)
{
    if (threadIdx.x < 8) out[threadIdx.x] = tanhf(accum[threadIdx.x] / accum[8]);
}

// ---------------------------------------------------------------------------
extern "C" void kernel_launch(void* const* d_in, const int* in_sizes, int n_in,
                              void* d_out, int out_size, void* d_ws, size_t ws_size,
                              hipStream_t stream)
{
    const float* feat  = (const float*)d_in[0];
    const int*   xnode = (const int*)d_in[1];
    const int*   xneis = (const int*)d_in[2];
    const int*   etype = (const int*)d_in[3];
    const float* dg    = (const float*)d_in[4];
    const float* Hinit = (const float*)d_in[5];
    const float* Wxi   = (const float*)d_in[6];
    const float* bxi   = (const float*)d_in[7];
    const float* Wrou  = (const float*)d_in[8];
    const float* brou  = (const float*)d_in[9];
    const float* W1    = (const float*)d_in[10];
    const float* b1    = (const float*)d_in[11];

    char* ws = (char*)d_ws;
    auto alloc = [&](size_t bytes) -> char* {
        char* p = ws; ws += (bytes + 255) & ~(size_t)255; return p;
    };
    // Budget: ~255 MB total (fits 256 MiB ws)
    ushort* Acsr    = (ushort*)alloc((size_t)E * 64 * 2);     // 204.8 MB
    ushort* PQ      = (ushort*)alloc((size_t)V * 128 * 2);    // 25.6 MB (bf16)
    float*  B0      = (float*)alloc((size_t)V * 8 * 4);       // 3.2 MB
    float*  B1      = (float*)alloc((size_t)V * 8 * 4);       // 3.2 MB
    float*  Bsum    = (float*)alloc((size_t)V * 8 * 4);       // 3.2 MB
    int*    eid     = (int*)alloc((size_t)E * 4);             // 6.4 MB
    int*    esrc    = (int*)alloc((size_t)E * 4);             // 6.4 MB
    int*    count   = (int*)alloc((size_t)2 * V * 4);         // 0.8 MB (count+cursor)
    int*    cursor  = count + V;
    int*    scanned = (int*)alloc((size_t)V * 4);
    int*    rowptr  = (int*)alloc((size_t)(V + 1) * 4);
    int*    blocksum= (int*)alloc(512 * 4);
    int*    tops    = (int*)alloc(512 * 4);
    float*  logits  = (float*)alloc((size_t)V * 4);
    float*  pmax    = (float*)alloc(256 * 4);
    float*  Mp      = (float*)alloc(16);
    float*  accum   = (float*)alloc(64);

    hipMemsetAsync(count, 0, (size_t)2 * V * 4, stream);
    hist_kernel<<<(E + 255) / 256, 256, 0, stream>>>(xneis, count);
    scan_block_kernel<<<NB, 256, 0, stream>>>(count, scanned, blocksum);
    scan_tops_kernel<<<1, 512, 0, stream>>>(blocksum, tops, rowptr);
    add_offsets_kernel<<<NB, 256, 0, stream>>>(scanned, tops, rowptr);
    scatter_kernel<<<(E + 255) / 256, 256, 0, stream>>>(xnode, xneis, rowptr, cursor, eid, esrc);
    pq_kernel<<<(V / 16 + 3) / 4, 256, 0, stream>>>(feat, Wxi, PQ);
    bsum_kernel<<<NB, 256, 0, stream>>>(feat, count, Wrou, brou, Bsum);
    edge_kernel<<<(int)(((size_t)E * 16 + 255) / 256), 256, 0, stream>>>(
        eid, xnode, xneis, etype, dg, rowptr, PQ, Wxi, bxi, Acsr);

    const float* Hcur = Hinit;
    float* bufs[2] = {B0, B1};
    for (int t = 0; t < 4; ++t) {
        float* Hn = bufs[t & 1];
        step_kernel<<<(V + 3) / 4, 256, 0, stream>>>(Hcur, Hn, Acsr, esrc, rowptr, Bsum);
        Hcur = Hn;
    }

    logits_kernel<<<NB, 256, 0, stream>>>(Hcur, W1, b1, logits);
    reduce_max_kernel<<<256, 256, 0, stream>>>(logits, pmax);
    final_max_kernel<<<1, 256, 0, stream>>>(pmax, Mp);
    hipMemsetAsync(accum, 0, 64, stream);
    sum_kernel<<<256, 256, 0, stream>>>(Hcur, logits, Mp, accum);
    final_kernel<<<1, 64, 0, stream>>>(accum, (float*)d_out);
}

// Round 8
// 793.521 us; speedup vs baseline: 1.0341x; 1.0341x over previous
//
#include <hip/hip_runtime.h>
#include <hip/hip_bf16.h>

constexpr int V   = 100000;
constexpr int E   = 1600000;
constexpr int NET = 10;
constexpr int KXW = 138;              // W_xi row length (2*64+10)
constexpr int NB  = (V + 255) / 256;  // 391 blocks over nodes
constexpr float MUS = 0.1125f;        // MU / S

typedef __attribute__((ext_vector_type(8))) short short8;
typedef __attribute__((ext_vector_type(4))) float float4v;

__device__ __forceinline__ float fast_tanh(float x) {
    return 1.0f - 2.0f / (__expf(2.0f * x) + 1.0f);
}
__device__ __forceinline__ float bflo(unsigned u) { return __uint_as_float(u << 16); }
__device__ __forceinline__ float bfhi(unsigned u) { return __uint_as_float(u & 0xffff0000u); }
__device__ __forceinline__ short f2bf(float x) {
    union { __hip_bfloat16 b; short s; } u; u.b = __float2bfloat16(x); return u.s;
}

// ---------------------------------------------------------------------------
// CSR build: histogram over RAW 1-indexed X_Neis (drop id >= V)
// ---------------------------------------------------------------------------
__global__ __launch_bounds__(256) void hist_kernel(
    const int* __restrict__ xneis, int* __restrict__ count)
{
    int e = blockIdx.x * 256 + threadIdx.x;
    if (e >= E) return;
    int nr = xneis[e];
    if (nr < V) atomicAdd(&count[nr], 1);
}

__global__ __launch_bounds__(256) void scan_block_kernel(
    const int* __restrict__ count, int* __restrict__ scanned, int* __restrict__ blocksum)
{
    __shared__ int s[256];
    int tid = threadIdx.x;
    int i = blockIdx.x * 256 + tid;
    int v = (i < V) ? count[i] : 0;
    s[tid] = v; __syncthreads();
    #pragma unroll
    for (int off = 1; off < 256; off <<= 1) {
        int t = (tid >= off) ? s[tid - off] : 0;
        __syncthreads();
        s[tid] += t;
        __syncthreads();
    }
    if (i < V) scanned[i] = s[tid] - v;          // block-exclusive
    if (tid == 255) blocksum[blockIdx.x] = s[255];
}

__global__ __launch_bounds__(512) void scan_tops_kernel(
    const int* __restrict__ blocksum, int* __restrict__ tops, int* __restrict__ rowptr)
{
    __shared__ int s[512];
    int tid = threadIdx.x;
    int v = (tid < NB) ? blocksum[tid] : 0;
    s[tid] = v; __syncthreads();
    #pragma unroll
    for (int off = 1; off < 512; off <<= 1) {
        int t = (tid >= off) ? s[tid - off] : 0;
        __syncthreads();
        s[tid] += t;
        __syncthreads();
    }
    if (tid < NB) tops[tid] = s[tid] - v;        // exclusive
    if (tid == 511) rowptr[V] = s[511];          // total kept edges
}

__global__ __launch_bounds__(256) void add_offsets_kernel(
    const int* __restrict__ scanned, const int* __restrict__ tops, int* __restrict__ rowptr)
{
    int i = blockIdx.x * 256 + threadIdx.x;
    if (i < V) rowptr[i] = scanned[i] + tops[blockIdx.x];
}

// Pre-pack per-CSR-slot metadata: meta[p] = { src | (et<<20), bits(MUS/dg) }.
// All step-kernel metadata reads become SEQUENTIAL 8 B loads (the round-7
// eid[p] indirection caused 410 MB of random 4 B gather line-fetches).
__global__ __launch_bounds__(256) void scatter_kernel(
    const int* __restrict__ xnode, const int* __restrict__ xneis,
    const int* __restrict__ etype, const float* __restrict__ dg,
    const int* __restrict__ rowptr, int* __restrict__ cursor,
    uint2* __restrict__ meta)
{
    int e = blockIdx.x * 256 + threadIdx.x;
    if (e >= E) return;
    int nr = xneis[e];
    if (nr < V) {
        int p = rowptr[nr] + atomicAdd(&cursor[nr], 1);
        unsigned src = (unsigned)(xnode[e] - 1);
        unsigned et  = (unsigned)(etype[e] - 1);
        float sc = MUS / dg[e];
        meta[p] = make_uint2(src | (et << 20), __float_as_uint(sc));
    }
}

// ---------------------------------------------------------------------------
// Per-node bias sum: Bsum[v] = count[v] * tanh(W_rou·feat[v-1]+b)
// ---------------------------------------------------------------------------
__global__ __launch_bounds__(256) void bsum_kernel(
    const float* __restrict__ feat, const int* __restrict__ count,
    const float* __restrict__ Wrou, const float* __restrict__ brou,
    float* __restrict__ Bsum)
{
    __shared__ float Wl[512];
    __shared__ float bl[8];
    int tid = threadIdx.x;
    for (int i = tid; i < 512; i += 256) Wl[i] = Wrou[i];
    if (tid < 8) bl[tid] = brou[tid];
    __syncthreads();

    int v = blockIdx.x * 256 + tid;
    if (v >= V) return;
    int c = count[v];
    float out[8] = {0, 0, 0, 0, 0, 0, 0, 0};
    if (c > 0) {                                  // c>0 implies v >= 1
        const float4* f4 = (const float4*)(feat + (size_t)(v - 1) * 64);
        float acc[8];
        #pragma unroll
        for (int s = 0; s < 8; ++s) acc[s] = bl[s];
        #pragma unroll 4
        for (int k = 0; k < 16; ++k) {
            float4 x = f4[k];
            #pragma unroll
            for (int s = 0; s < 8; ++s) {
                const float* w = &Wl[s * 64 + k * 4];
                acc[s] += x.x * w[0] + x.y * w[1] + x.z * w[2] + x.w * w[3];
            }
        }
        float fc = (float)c;
        #pragma unroll
        for (int s = 0; s < 8; ++s) out[s] = fc * fast_tanh(acc[s]);
    }
    float4* O = (float4*)(Bsum + (size_t)v * 8);
    O[0] = make_float4(out[0], out[1], out[2], out[3]);
    O[1] = make_float4(out[4], out[5], out[6], out[7]);
}

// ---------------------------------------------------------------------------
// PQ GEMM (MFMA): PQ[v][0:64] = feat[v]·Wxi[:, 0:64]^T   (P part)
//                 PQ[v][64:128] = feat[v]·Wxi[:, 64:128]^T (Q part), bf16 out
// ---------------------------------------------------------------------------
__global__ __launch_bounds__(256) void pq_kernel(
    const float* __restrict__ feat, const float* __restrict__ Wxi,
    ushort* __restrict__ PQ)
{
    const int lane = threadIdx.x & 63, wave = threadIdx.x >> 6;
    const int quad = lane >> 4, l16 = lane & 15;

    short8 bP[4][2], bQ[4][2];
    #pragma unroll
    for (int nt = 0; nt < 4; ++nt) {
        #pragma unroll
        for (int ks = 0; ks < 2; ++ks) {
            const float* wp = Wxi + (size_t)(nt * 16 + l16) * KXW + ks * 32 + quad * 8;
            short8 p, q;
            #pragma unroll
            for (int j = 0; j < 8; ++j) { p[j] = f2bf(wp[j]); q[j] = f2bf(wp[64 + j]); }
            bP[nt][ks] = p; bQ[nt][ks] = q;
        }
    }

    int t = blockIdx.x * 4 + wave;
    if (t >= V / 16) return;
    int v0 = t * 16;

    const float* fp = feat + (size_t)(v0 + l16) * 64 + quad * 8;
    short8 a0, a1;
    #pragma unroll
    for (int j = 0; j < 8; ++j) { a0[j] = f2bf(fp[j]); a1[j] = f2bf(fp[32 + j]); }

    float4v accP[4], accQ[4];
    #pragma unroll
    for (int nt = 0; nt < 4; ++nt) {
        float4v z = {0.f, 0.f, 0.f, 0.f};
        z = __builtin_amdgcn_mfma_f32_16x16x32_bf16(a0, bP[nt][0], z, 0, 0, 0);
        z = __builtin_amdgcn_mfma_f32_16x16x32_bf16(a1, bP[nt][1], z, 0, 0, 0);
        accP[nt] = z;
        float4v w = {0.f, 0.f, 0.f, 0.f};
        w = __builtin_amdgcn_mfma_f32_16x16x32_bf16(a0, bQ[nt][0], w, 0, 0, 0);
        w = __builtin_amdgcn_mfma_f32_16x16x32_bf16(a1, bQ[nt][1], w, 0, 0, 0);
        accQ[nt] = w;
    }

    #pragma unroll
    for (int r = 0; r < 4; ++r) {
        ushort* row = PQ + (size_t)(v0 + quad * 4 + r) * 128;
        #pragma unroll
        for (int nt = 0; nt < 4; ++nt) {
            row[nt * 16 + l16]      = (ushort)f2bf(accP[nt][r]);
            row[64 + nt * 16 + l16] = (ushort)f2bf(accQ[nt][r]);
        }
    }
}

// ---------------------------------------------------------------------------
// Fused step: recompute A on the fly from PQ (A is never materialized).
// One wave per node v. lane = el*16 + j, j = r*2 + ch, flat = r*8 + ch*4.
// Each lane handles components [flat, flat+4) of 4 edges in flight:
//   A[n] = tanh(P[src][n] + Q[v][n] + WetB[et][n]) * sc,  acc += A[n]·He[n%8...]
// Reduce: shfl_xor 1 (c-halves), 16, 32 (edge slots).
// ---------------------------------------------------------------------------
__global__ __launch_bounds__(256) void step_kernel(
    const float* __restrict__ Hin, float* __restrict__ Hout,
    const uint2* __restrict__ meta, const int* __restrict__ rowptr,
    const ushort* __restrict__ PQ, const float* __restrict__ Wxi,
    const float* __restrict__ bxi, const float* __restrict__ Bsum)
{
    __shared__ float WetB[NET * 64];
    int tid = threadIdx.x;
    for (int i = tid; i < NET * 64; i += 256) {
        int et = i >> 6, n = i & 63;
        WetB[i] = Wxi[n * KXW + 128 + et] + bxi[n];
    }
    __syncthreads();

    int v = blockIdx.x * 4 + (tid >> 6);
    if (v >= V) return;
    int lane = tid & 63;
    int el = lane >> 4, j = lane & 15;
    int r = j >> 1, ch = j & 1;
    int flat = r * 8 + ch * 4;            // this lane's 4 components of A

    int p0 = rowptr[v], p1 = rowptr[v + 1];

    // Q[v] components (constant across this node's edges)
    float q0, q1, q2, q3;
    {
        uint2 qu = *(const uint2*)(PQ + (size_t)v * 128 + 64 + flat);
        q0 = bflo(qu.x); q1 = bfhi(qu.x);
        q2 = bflo(qu.y); q3 = bfhi(qu.y);
    }
    const float* wb = &WetB[flat];        // + et*64 at use

    float acc = 0.0f;
    for (int p = p0 + el; p < p1; p += 4) {
        uint2 m = meta[p];
        int src = m.x & 0xFFFFF;
        int et  = m.x >> 20;
        float sc = __uint_as_float(m.y);

        uint2 pu = *(const uint2*)(PQ + (size_t)src * 128 + flat);
        float4 he = *(const float4*)(Hin + (size_t)src * 8 + ch * 4);
        const float* w = wb + et * 64;

        float a0 = fast_tanh(bflo(pu.x) + q0 + w[0]);
        float a1 = fast_tanh(bfhi(pu.x) + q1 + w[1]);
        float a2 = fast_tanh(bflo(pu.y) + q2 + w[2]);
        float a3 = fast_tanh(bfhi(pu.y) + q3 + w[3]);

        acc += sc * (a0 * he.x + a1 * he.y + a2 * he.z + a3 * he.w);
    }
    acc += __shfl_xor(acc, 1);            // combine c-halves (same r)
    acc += __shfl_xor(acc, 16);           // combine edge slots
    acc += __shfl_xor(acc, 32);
    if (lane < 16 && ch == 0)
        Hout[(size_t)v * 8 + r] = acc + Bsum[(size_t)v * 8 + r];
}

// ---------------------------------------------------------------------------
// Epilogue
// ---------------------------------------------------------------------------
__global__ __launch_bounds__(256) void logits_kernel(
    const float* __restrict__ H, const float* __restrict__ W1,
    const float* __restrict__ b1, float* __restrict__ logits)
{
    int v = blockIdx.x * 256 + threadIdx.x;
    if (v >= V) return;
    float4 w0 = ((const float4*)W1)[0], w1 = ((const float4*)W1)[1];
    const float4* H4 = (const float4*)(H + (size_t)v * 8);
    float4 h0 = H4[0], h1 = H4[1];
    logits[v] = b1[0]
              + h0.x * w0.x + h0.y * w0.y + h0.z * w0.z + h0.w * w0.w
              + h1.x * w1.x + h1.y * w1.y + h1.z * w1.z + h1.w * w1.w;
}

__global__ __launch_bounds__(256) void reduce_max_kernel(
    const float* __restrict__ logits, float* __restrict__ partial)
{
    float m = -INFINITY;
    for (int v = blockIdx.x * 256 + threadIdx.x; v < V; v += 256 * 256)
        m = fmaxf(m, logits[v]);
    #pragma unroll
    for (int o = 32; o > 0; o >>= 1) m = fmaxf(m, __shfl_down(m, o));
    __shared__ float sm[4];
    if ((threadIdx.x & 63) == 0) sm[threadIdx.x >> 6] = m;
    __syncthreads();
    if (threadIdx.x == 0)
        partial[blockIdx.x] = fmaxf(fmaxf(sm[0], sm[1]), fmaxf(sm[2], sm[3]));
}

__global__ __launch_bounds__(256) void final_max_kernel(
    const float* __restrict__ partial, float* __restrict__ M)
{
    float m = partial[threadIdx.x];
    #pragma unroll
    for (int o = 32; o > 0; o >>= 1) m = fmaxf(m, __shfl_down(m, o));
    __shared__ float sm[4];
    if ((threadIdx.x & 63) == 0) sm[threadIdx.x >> 6] = m;
    __syncthreads();
    if (threadIdx.x == 0) *M = fmaxf(fmaxf(sm[0], sm[1]), fmaxf(sm[2], sm[3]));
}

__global__ __launch_bounds__(256) void sum_kernel(
    const float* __restrict__ H, const float* __restrict__ logits,
    const float* __restrict__ Mp, float* __restrict__ accum)
{
    const float M = *Mp;
    float se = 0.0f;
    float sh[8] = {0, 0, 0, 0, 0, 0, 0, 0};
    for (int v = blockIdx.x * 256 + threadIdx.x; v < V; v += 256 * 256) {
        float w = __expf(logits[v] - M);
        se += w;
        const float4* H4 = (const float4*)(H + (size_t)v * 8);
        float4 h0 = H4[0], h1 = H4[1];
        sh[0] += w * h0.x; sh[1] += w * h0.y; sh[2] += w * h0.z; sh[3] += w * h0.w;
        sh[4] += w * h1.x; sh[5] += w * h1.y; sh[6] += w * h1.z; sh[7] += w * h1.w;
    }
    #pragma unroll
    for (int o = 32; o > 0; o >>= 1) {
        se += __shfl_down(se, o);
        #pragma unroll
        for (int i = 0; i < 8; ++i) sh[i] += __shfl_down(sh[i], o);
    }
    if ((threadIdx.x & 63) == 0) {
        atomicAdd(&accum[8], se);
        #pragma unroll
        for (int i = 0; i < 8; ++i) atomicAdd(&accum[i], sh[i]);
    }
}

__global__ void final_kernel(const float* __restrict__ accum, float* __restrict__ out)
{
    if (threadIdx.x < 8) out[threadIdx.x] = tanhf(accum[threadIdx.x] / accum[8]);
}

// ---------------------------------------------------------------------------
extern "C" void kernel_launch(void* const* d_in, const int* in_sizes, int n_in,
                              void* d_out, int out_size, void* d_ws, size_t ws_size,
                              hipStream_t stream)
{
    const float* feat  = (const float*)d_in[0];
    const int*   xnode = (const int*)d_in[1];
    const int*   xneis = (const int*)d_in[2];
    const int*   etype = (const int*)d_in[3];
    const float* dg    = (const float*)d_in[4];
    const float* Hinit = (const float*)d_in[5];
    const float* Wxi   = (const float*)d_in[6];
    const float* bxi   = (const float*)d_in[7];
    const float* Wrou  = (const float*)d_in[8];
    const float* brou  = (const float*)d_in[9];
    const float* W1    = (const float*)d_in[10];
    const float* b1    = (const float*)d_in[11];

    char* ws = (char*)d_ws;
    auto alloc = [&](size_t bytes) -> char* {
        char* p = ws; ws += (bytes + 255) & ~(size_t)255; return p;
    };
    // Budget: ~54 MB total (Acsr eliminated — A recomputed in-step from PQ)
    ushort* PQ      = (ushort*)alloc((size_t)V * 128 * 2);    // 25.6 MB (bf16)
    uint2*  meta    = (uint2*)alloc((size_t)E * 8);           // 12.8 MB
    float*  B0      = (float*)alloc((size_t)V * 8 * 4);       // 3.2 MB
    float*  B1      = (float*)alloc((size_t)V * 8 * 4);       // 3.2 MB
    float*  Bsum    = (float*)alloc((size_t)V * 8 * 4);       // 3.2 MB
    int*    count   = (int*)alloc((size_t)2 * V * 4);         // 0.8 MB (count+cursor)
    int*    cursor  = count + V;
    int*    scanned = (int*)alloc((size_t)V * 4);
    int*    rowptr  = (int*)alloc((size_t)(V + 1) * 4);
    int*    blocksum= (int*)alloc(512 * 4);
    int*    tops    = (int*)alloc(512 * 4);
    float*  logits  = (float*)alloc((size_t)V * 4);
    float*  pmax    = (float*)alloc(256 * 4);
    float*  Mp      = (float*)alloc(16);
    float*  accum   = (float*)alloc(64);

    hipMemsetAsync(count, 0, (size_t)2 * V * 4, stream);
    hist_kernel<<<(E + 255) / 256, 256, 0, stream>>>(xneis, count);
    scan_block_kernel<<<NB, 256, 0, stream>>>(count, scanned, blocksum);
    scan_tops_kernel<<<1, 512, 0, stream>>>(blocksum, tops, rowptr);
    add_offsets_kernel<<<NB, 256, 0, stream>>>(scanned, tops, rowptr);
    scatter_kernel<<<(E + 255) / 256, 256, 0, stream>>>(xnode, xneis, etype, dg,
                                                        rowptr, cursor, meta);
    pq_kernel<<<(V / 16 + 3) / 4, 256, 0, stream>>>(feat, Wxi, PQ);
    bsum_kernel<<<NB, 256, 0, stream>>>(feat, count, Wrou, brou, Bsum);

    const float* Hcur = Hinit;
    float* bufs[2] = {B0, B1};
    for (int t = 0; t < 4; ++t) {
        float* Hn = bufs[t & 1];
        step_kernel<<<(V + 3) / 4, 256, 0, stream>>>(Hcur, Hn, meta, rowptr,
                                                     PQ, Wxi, bxi, Bsum);
        Hcur = Hn;
    }

    logits_kernel<<<NB, 256, 0, stream>>>(Hcur, W1, b1, logits);
    reduce_max_kernel<<<256, 256, 0, stream>>>(logits, pmax);
    final_max_kernel<<<1, 256, 0, stream>>>(pmax, Mp);
    hipMemsetAsync(accum, 0, 64, stream);
    sum_kernel<<<256, 256, 0, stream>>>(Hcur, logits, Mp, accum);
    final_kernel<<<1, 64, 0, stream>>>(accum, (float*)d_out);
}

// Round 9
// 700.560 us; speedup vs baseline: 1.1713x; 1.1327x over previous
//
#include <hip/hip_runtime.h>
#include <hip/hip_bf16.h>

constexpr int V   = 100000;
constexpr int E   = 1600000;
constexpr int NET = 10;
constexpr int KXW = 138;              // W_xi row length (2*64+10)
constexpr int NB  = (V + 255) / 256;  // 391 blocks over nodes
constexpr float MUS = 0.1125f;        // MU / S

typedef __attribute__((ext_vector_type(8))) short short8;
typedef __attribute__((ext_vector_type(4))) float float4v;

__device__ __forceinline__ float fast_tanh(float x) {
    return 1.0f - 2.0f / (__expf(2.0f * x) + 1.0f);
}
__device__ __forceinline__ float bflo(unsigned u) { return __uint_as_float(u << 16); }
__device__ __forceinline__ float bfhi(unsigned u) { return __uint_as_float(u & 0xffff0000u); }
__device__ __forceinline__ short f2bf(float x) {
    union { __hip_bfloat16 b; short s; } u; u.b = __float2bfloat16(x); return u.s;
}

// ---------------------------------------------------------------------------
// CSR build: histogram over RAW 1-indexed X_Neis (drop id >= V)
// ---------------------------------------------------------------------------
__global__ __launch_bounds__(256) void hist_kernel(
    const int* __restrict__ xneis, int* __restrict__ count)
{
    int e = blockIdx.x * 256 + threadIdx.x;
    if (e >= E) return;
    int nr = xneis[e];
    if (nr < V) atomicAdd(&count[nr], 1);
}

__global__ __launch_bounds__(256) void scan_block_kernel(
    const int* __restrict__ count, int* __restrict__ scanned, int* __restrict__ blocksum)
{
    __shared__ int s[256];
    int tid = threadIdx.x;
    int i = blockIdx.x * 256 + tid;
    int v = (i < V) ? count[i] : 0;
    s[tid] = v; __syncthreads();
    #pragma unroll
    for (int off = 1; off < 256; off <<= 1) {
        int t = (tid >= off) ? s[tid - off] : 0;
        __syncthreads();
        s[tid] += t;
        __syncthreads();
    }
    if (i < V) scanned[i] = s[tid] - v;          // block-exclusive
    if (tid == 255) blocksum[blockIdx.x] = s[255];
}

__global__ __launch_bounds__(512) void scan_tops_kernel(
    const int* __restrict__ blocksum, int* __restrict__ tops, int* __restrict__ rowptr)
{
    __shared__ int s[512];
    int tid = threadIdx.x;
    int v = (tid < NB) ? blocksum[tid] : 0;
    s[tid] = v; __syncthreads();
    #pragma unroll
    for (int off = 1; off < 512; off <<= 1) {
        int t = (tid >= off) ? s[tid - off] : 0;
        __syncthreads();
        s[tid] += t;
        __syncthreads();
    }
    if (tid < NB) tops[tid] = s[tid] - v;        // exclusive
    if (tid == 511) rowptr[V] = s[511];          // total kept edges
}

__global__ __launch_bounds__(256) void add_offsets_kernel(
    const int* __restrict__ scanned, const int* __restrict__ tops, int* __restrict__ rowptr)
{
    int i = blockIdx.x * 256 + threadIdx.x;
    if (i < V) rowptr[i] = scanned[i] + tops[blockIdx.x];
}

// Packed per-CSR-slot metadata (4 B): src (17 b) | et (4 b) | dg-1 (6 b).
// dg_list values are exact integers 1..64; sc = MUS/dg comes from an LDS table.
__global__ __launch_bounds__(256) void scatter_kernel(
    const int* __restrict__ xnode, const int* __restrict__ xneis,
    const int* __restrict__ etype, const float* __restrict__ dg,
    const int* __restrict__ rowptr, int* __restrict__ cursor,
    unsigned* __restrict__ meta)
{
    int e = blockIdx.x * 256 + threadIdx.x;
    if (e >= E) return;
    int nr = xneis[e];
    if (nr < V) {
        int p = rowptr[nr] + atomicAdd(&cursor[nr], 1);
        unsigned src = (unsigned)(xnode[e] - 1);
        unsigned et  = (unsigned)(etype[e] - 1);
        unsigned dgi = (unsigned)dg[e] - 1;        // 0..63, exact
        meta[p] = src | (et << 17) | (dgi << 21);
    }
}

// ---------------------------------------------------------------------------
// Per-node bias sum: Bsum[v] = count[v] * tanh(W_rou·feat[v-1]+b)
// ---------------------------------------------------------------------------
__global__ __launch_bounds__(256) void bsum_kernel(
    const float* __restrict__ feat, const int* __restrict__ count,
    const float* __restrict__ Wrou, const float* __restrict__ brou,
    float* __restrict__ Bsum)
{
    __shared__ float Wl[512];
    __shared__ float bl[8];
    int tid = threadIdx.x;
    for (int i = tid; i < 512; i += 256) Wl[i] = Wrou[i];
    if (tid < 8) bl[tid] = brou[tid];
    __syncthreads();

    int v = blockIdx.x * 256 + tid;
    if (v >= V) return;
    int c = count[v];
    float out[8] = {0, 0, 0, 0, 0, 0, 0, 0};
    if (c > 0) {                                  // c>0 implies v >= 1
        const float4* f4 = (const float4*)(feat + (size_t)(v - 1) * 64);
        float acc[8];
        #pragma unroll
        for (int s = 0; s < 8; ++s) acc[s] = bl[s];
        #pragma unroll 4
        for (int k = 0; k < 16; ++k) {
            float4 x = f4[k];
            #pragma unroll
            for (int s = 0; s < 8; ++s) {
                const float* w = &Wl[s * 64 + k * 4];
                acc[s] += x.x * w[0] + x.y * w[1] + x.z * w[2] + x.w * w[3];
            }
        }
        float fc = (float)c;
        #pragma unroll
        for (int s = 0; s < 8; ++s) out[s] = fc * fast_tanh(acc[s]);
    }
    float4* O = (float4*)(Bsum + (size_t)v * 8);
    O[0] = make_float4(out[0], out[1], out[2], out[3]);
    O[1] = make_float4(out[4], out[5], out[6], out[7]);
}

// ---------------------------------------------------------------------------
// PQ GEMM (MFMA): PQ[v][0:64] = feat[v]·Wxi[:, 0:64]^T   (P part)
//                 PQ[v][64:128] = feat[v]·Wxi[:, 64:128]^T (Q part), bf16 out
// ---------------------------------------------------------------------------
__global__ __launch_bounds__(256) void pq_kernel(
    const float* __restrict__ feat, const float* __restrict__ Wxi,
    ushort* __restrict__ PQ)
{
    const int lane = threadIdx.x & 63, wave = threadIdx.x >> 6;
    const int quad = lane >> 4, l16 = lane & 15;

    short8 bP[4][2], bQ[4][2];
    #pragma unroll
    for (int nt = 0; nt < 4; ++nt) {
        #pragma unroll
        for (int ks = 0; ks < 2; ++ks) {
            const float* wp = Wxi + (size_t)(nt * 16 + l16) * KXW + ks * 32 + quad * 8;
            short8 p, q;
            #pragma unroll
            for (int j = 0; j < 8; ++j) { p[j] = f2bf(wp[j]); q[j] = f2bf(wp[64 + j]); }
            bP[nt][ks] = p; bQ[nt][ks] = q;
        }
    }

    int t = blockIdx.x * 4 + wave;
    if (t >= V / 16) return;
    int v0 = t * 16;

    const float* fp = feat + (size_t)(v0 + l16) * 64 + quad * 8;
    short8 a0, a1;
    #pragma unroll
    for (int j = 0; j < 8; ++j) { a0[j] = f2bf(fp[j]); a1[j] = f2bf(fp[32 + j]); }

    float4v accP[4], accQ[4];
    #pragma unroll
    for (int nt = 0; nt < 4; ++nt) {
        float4v z = {0.f, 0.f, 0.f, 0.f};
        z = __builtin_amdgcn_mfma_f32_16x16x32_bf16(a0, bP[nt][0], z, 0, 0, 0);
        z = __builtin_amdgcn_mfma_f32_16x16x32_bf16(a1, bP[nt][1], z, 0, 0, 0);
        accP[nt] = z;
        float4v w = {0.f, 0.f, 0.f, 0.f};
        w = __builtin_amdgcn_mfma_f32_16x16x32_bf16(a0, bQ[nt][0], w, 0, 0, 0);
        w = __builtin_amdgcn_mfma_f32_16x16x32_bf16(a1, bQ[nt][1], w, 0, 0, 0);
        accQ[nt] = w;
    }

    #pragma unroll
    for (int r = 0; r < 4; ++r) {
        ushort* row = PQ + (size_t)(v0 + quad * 4 + r) * 128;
        #pragma unroll
        for (int nt = 0; nt < 4; ++nt) {
            row[nt * 16 + l16]      = (ushort)f2bf(accP[nt][r]);
            row[64 + nt * 16 + l16] = (ushort)f2bf(accQ[nt][r]);
        }
    }
}

// ---------------------------------------------------------------------------
// Fused step, 8 edges in flight per wave: lane = el*8 + s (el edge slot,
// s output component). Each lane computes the full row-s dot for its edges:
//   out[v][s] += sc_e * sum_j tanh(P[src][s*8+j] + Q[v][s*8+j] + WetB[et][s*8+j]) * He[j]
// P-row read: one uint4 (16 B)/lane, 8 lanes cover the 128 B row. He is an
// 8-lane broadcast. Reduce over el via shfl_xor 8/16/32.
// ---------------------------------------------------------------------------
__global__ __launch_bounds__(256) void step_kernel(
    const float* __restrict__ Hin, float* __restrict__ Hout,
    const unsigned* __restrict__ meta, const int* __restrict__ rowptr,
    const ushort* __restrict__ PQ, const float* __restrict__ Wxi,
    const float* __restrict__ bxi, const float* __restrict__ Bsum)
{
    __shared__ float WetB[NET * 64];
    __shared__ float scT[64];
    int tid = threadIdx.x;
    for (int i = tid; i < NET * 64; i += 256) {
        int et = i >> 6, n = i & 63;
        WetB[i] = Wxi[n * KXW + 128 + et] + bxi[n];
    }
    if (tid < 64) scT[tid] = MUS / (float)(tid + 1);
    __syncthreads();

    int v = blockIdx.x * 4 + (tid >> 6);
    if (v >= V) return;
    int lane = tid & 63;
    int el = lane >> 3, s = lane & 7;

    int p0 = rowptr[v], p1 = rowptr[v + 1];

    // Q components for this lane's row s (constant over the node's edges)
    float q0, q1, q2, q3, q4, q5, q6, q7;
    {
        uint4 qu = *(const uint4*)(PQ + (size_t)v * 128 + 64 + s * 8);
        q0 = bflo(qu.x); q1 = bfhi(qu.x); q2 = bflo(qu.y); q3 = bfhi(qu.y);
        q4 = bflo(qu.z); q5 = bfhi(qu.z); q6 = bflo(qu.w); q7 = bfhi(qu.w);
    }

    float acc = 0.0f;
    for (int p = p0 + el; p < p1; p += 8) {
        unsigned m = meta[p];
        int src = m & 0x1FFFF;
        int et  = (m >> 17) & 0xF;
        float sc = scT[m >> 21];

        uint4 pu = *(const uint4*)(PQ + (size_t)src * 128 + s * 8);
        float4 h0 = *(const float4*)(Hin + (size_t)src * 8);
        float4 h1 = *(const float4*)(Hin + (size_t)src * 8 + 4);
        const float* w = &WetB[et * 64 + s * 8];

        float d;
        d  = fast_tanh(bflo(pu.x) + q0 + w[0]) * h0.x;
        d += fast_tanh(bfhi(pu.x) + q1 + w[1]) * h0.y;
        d += fast_tanh(bflo(pu.y) + q2 + w[2]) * h0.z;
        d += fast_tanh(bfhi(pu.y) + q3 + w[3]) * h0.w;
        d += fast_tanh(bflo(pu.z) + q4 + w[4]) * h1.x;
        d += fast_tanh(bfhi(pu.z) + q5 + w[5]) * h1.y;
        d += fast_tanh(bflo(pu.w) + q6 + w[6]) * h1.z;
        d += fast_tanh(bfhi(pu.w) + q7 + w[7]) * h1.w;
        acc += sc * d;
    }
    acc += __shfl_xor(acc, 8);            // reduce over edge slots (el bits)
    acc += __shfl_xor(acc, 16);
    acc += __shfl_xor(acc, 32);
    if (el == 0)
        Hout[(size_t)v * 8 + s] = acc + Bsum[(size_t)v * 8 + s];
}

// ---------------------------------------------------------------------------
// Epilogue
// ---------------------------------------------------------------------------
__global__ __launch_bounds__(256) void logits_kernel(
    const float* __restrict__ H, const float* __restrict__ W1,
    const float* __restrict__ b1, float* __restrict__ logits)
{
    int v = blockIdx.x * 256 + threadIdx.x;
    if (v >= V) return;
    float4 w0 = ((const float4*)W1)[0], w1 = ((const float4*)W1)[1];
    const float4* H4 = (const float4*)(H + (size_t)v * 8);
    float4 h0 = H4[0], h1 = H4[1];
    logits[v] = b1[0]
              + h0.x * w0.x + h0.y * w0.y + h0.z * w0.z + h0.w * w0.w
              + h1.x * w1.x + h1.y * w1.y + h1.z * w1.z + h1.w * w1.w;
}

__global__ __launch_bounds__(256) void reduce_max_kernel(
    const float* __restrict__ logits, float* __restrict__ partial)
{
    float m = -INFINITY;
    for (int v = blockIdx.x * 256 + threadIdx.x; v < V; v += 256 * 256)
        m = fmaxf(m, logits[v]);
    #pragma unroll
    for (int o = 32; o > 0; o >>= 1) m = fmaxf(m, __shfl_down(m, o));
    __shared__ float sm[4];
    if ((threadIdx.x & 63) == 0) sm[threadIdx.x >> 6] = m;
    __syncthreads();
    if (threadIdx.x == 0)
        partial[blockIdx.x] = fmaxf(fmaxf(sm[0], sm[1]), fmaxf(sm[2], sm[3]));
}

__global__ __launch_bounds__(256) void final_max_kernel(
    const float* __restrict__ partial, float* __restrict__ M)
{
    float m = partial[threadIdx.x];
    #pragma unroll
    for (int o = 32; o > 0; o >>= 1) m = fmaxf(m, __shfl_down(m, o));
    __shared__ float sm[4];
    if ((threadIdx.x & 63) == 0) sm[threadIdx.x >> 6] = m;
    __syncthreads();
    if (threadIdx.x == 0) *M = fmaxf(fmaxf(sm[0], sm[1]), fmaxf(sm[2], sm[3]));
}

// Stage 1: 64 blocks write per-block partials (9 floats each) — NO atomics
// (the round-8 profile showed 1024-deep serialized atomic chains = 119 µs).
__global__ __launch_bounds__(256) void sum_kernel(
    const float* __restrict__ H, const float* __restrict__ logits,
    const float* __restrict__ Mp, float* __restrict__ partial)
{
    const float M = *Mp;
    float se = 0.0f;
    float sh[8] = {0, 0, 0, 0, 0, 0, 0, 0};
    for (int v = blockIdx.x * 256 + threadIdx.x; v < V; v += 64 * 256) {
        float w = __expf(logits[v] - M);
        se += w;
        const float4* H4 = (const float4*)(H + (size_t)v * 8);
        float4 h0 = H4[0], h1 = H4[1];
        sh[0] += w * h0.x; sh[1] += w * h0.y; sh[2] += w * h0.z; sh[3] += w * h0.w;
        sh[4] += w * h1.x; sh[5] += w * h1.y; sh[6] += w * h1.z; sh[7] += w * h1.w;
    }
    #pragma unroll
    for (int o = 32; o > 0; o >>= 1) {
        se += __shfl_xor(se, o);
        #pragma unroll
        for (int i = 0; i < 8; ++i) sh[i] += __shfl_xor(sh[i], o);
    }
    __shared__ float sm[4][9];
    int wv = threadIdx.x >> 6;
    if ((threadIdx.x & 63) == 0) {
        sm[wv][8] = se;
        #pragma unroll
        for (int i = 0; i < 8; ++i) sm[wv][i] = sh[i];
    }
    __syncthreads();
    if (threadIdx.x == 0) {
        #pragma unroll
        for (int i = 0; i < 9; ++i)
            partial[blockIdx.x * 12 + i] = sm[0][i] + sm[1][i] + sm[2][i] + sm[3][i];
    }
}

// Stage 2: one wave reduces the 64 partials and writes the final 8 outputs.
__global__ void final_kernel(const float* __restrict__ partial, float* __restrict__ out)
{
    int lane = threadIdx.x;               // 64 threads
    float vals[9];
    #pragma unroll
    for (int i = 0; i < 9; ++i) vals[i] = partial[lane * 12 + i];
    #pragma unroll
    for (int o = 1; o < 64; o <<= 1) {
        #pragma unroll
        for (int i = 0; i < 9; ++i) vals[i] += __shfl_xor(vals[i], o);
    }
    __shared__ float res[9];
    if (lane == 0) {
        #pragma unroll
        for (int i = 0; i < 9; ++i) res[i] = vals[i];
    }
    __syncthreads();
    if (lane < 8) out[lane] = tanhf(res[lane] / res[8]);
}

// ---------------------------------------------------------------------------
extern "C" void kernel_launch(void* const* d_in, const int* in_sizes, int n_in,
                              void* d_out, int out_size, void* d_ws, size_t ws_size,
                              hipStream_t stream)
{
    const float* feat  = (const float*)d_in[0];
    const int*   xnode = (const int*)d_in[1];
    const int*   xneis = (const int*)d_in[2];
    const int*   etype = (const int*)d_in[3];
    const float* dg    = (const float*)d_in[4];
    const float* Hinit = (const float*)d_in[5];
    const float* Wxi   = (const float*)d_in[6];
    const float* bxi   = (const float*)d_in[7];
    const float* Wrou  = (const float*)d_in[8];
    const float* brou  = (const float*)d_in[9];
    const float* W1    = (const float*)d_in[10];
    const float* b1    = (const float*)d_in[11];

    char* ws = (char*)d_ws;
    auto alloc = [&](size_t bytes) -> char* {
        char* p = ws; ws += (bytes + 255) & ~(size_t)255; return p;
    };
    // Budget: ~48 MB total
    ushort*   PQ      = (ushort*)alloc((size_t)V * 128 * 2);  // 25.6 MB (bf16)
    unsigned* meta    = (unsigned*)alloc((size_t)E * 4);      // 6.4 MB (packed)
    float*    B0      = (float*)alloc((size_t)V * 8 * 4);     // 3.2 MB
    float*    B1      = (float*)alloc((size_t)V * 8 * 4);     // 3.2 MB
    float*    Bsum    = (float*)alloc((size_t)V * 8 * 4);     // 3.2 MB
    int*      count   = (int*)alloc((size_t)2 * V * 4);       // 0.8 MB (count+cursor)
    int*      cursor  = count + V;
    int*      scanned = (int*)alloc((size_t)V * 4);
    int*      rowptr  = (int*)alloc((size_t)(V + 1) * 4);
    int*      blocksum= (int*)alloc(512 * 4);
    int*      tops    = (int*)alloc(512 * 4);
    float*    logits  = (float*)alloc((size_t)V * 4);
    float*    pmax    = (float*)alloc(256 * 4);
    float*    Mp      = (float*)alloc(16);
    float*    spart   = (float*)alloc(64 * 12 * 4);

    hipMemsetAsync(count, 0, (size_t)2 * V * 4, stream);
    hist_kernel<<<(E + 255) / 256, 256, 0, stream>>>(xneis, count);
    scan_block_kernel<<<NB, 256, 0, stream>>>(count, scanned, blocksum);
    scan_tops_kernel<<<1, 512, 0, stream>>>(blocksum, tops, rowptr);
    add_offsets_kernel<<<NB, 256, 0, stream>>>(scanned, tops, rowptr);
    scatter_kernel<<<(E + 255) / 256, 256, 0, stream>>>(xnode, xneis, etype, dg,
                                                        rowptr, cursor, meta);
    pq_kernel<<<(V / 16 + 3) / 4, 256, 0, stream>>>(feat, Wxi, PQ);
    bsum_kernel<<<NB, 256, 0, stream>>>(feat, count, Wrou, brou, Bsum);

    const float* Hcur = Hinit;
    float* bufs[2] = {B0, B1};
    for (int t = 0; t < 4; ++t) {
        float* Hn = bufs[t & 1];
        step_kernel<<<(V + 3) / 4, 256, 0, stream>>>(Hcur, Hn, meta, rowptr,
                                                     PQ, Wxi, bxi, Bsum);
        Hcur = Hn;
    }

    logits_kernel<<<NB, 256, 0, stream>>>(Hcur, W1, b1, logits);
    reduce_max_kernel<<<256, 256, 0, stream>>>(logits, pmax);
    final_max_kernel<<<1, 256, 0, stream>>>(pmax, Mp);
    sum_kernel<<<64, 256, 0, stream>>>(Hcur, logits, Mp, spart);
    final_kernel<<<1, 64, 0, stream>>>(spart, (float*)d_out);
}

// Round 10
// 581.076 us; speedup vs baseline: 1.4121x; 1.2056x over previous
//
#include <hip/hip_runtime.h>
#include <hip/hip_bf16.h>

constexpr int V   = 100000;
constexpr int E   = 1600000;
constexpr int NET = 10;
constexpr int KXW = 138;              // W_xi row length (2*64+10)
constexpr int NB  = (V + 255) / 256;  // 391 blocks over nodes
constexpr float MUS = 0.1125f;        // MU / S

typedef __attribute__((ext_vector_type(8))) short short8;
typedef __attribute__((ext_vector_type(4))) float float4v;

// tanh via exp + RAW v_rcp_f32. Without -ffast-math, `a/b` emits the full
// IEEE div sequence (div_scale/div_fmas/div_fixup ~10 insts) — that was ~half
// the round-9 step VALU time. rcp is 1-ulp; saturation: exp=Inf -> rcp=0 -> 1.
__device__ __forceinline__ float fast_tanh(float x) {
    return 1.0f - 2.0f * __builtin_amdgcn_rcpf(__expf(2.0f * x) + 1.0f);
}
__device__ __forceinline__ float bflo(unsigned u) { return __uint_as_float(u << 16); }
__device__ __forceinline__ float bfhi(unsigned u) { return __uint_as_float(u & 0xffff0000u); }
__device__ __forceinline__ short f2bf(float x) {
    union { __hip_bfloat16 b; short s; } u; u.b = __float2bfloat16(x); return u.s;
}

// ---------------------------------------------------------------------------
// CSR build: histogram over RAW 1-indexed X_Neis (drop id >= V)
// ---------------------------------------------------------------------------
__global__ __launch_bounds__(256) void hist_kernel(
    const int* __restrict__ xneis, int* __restrict__ count)
{
    int e = blockIdx.x * 256 + threadIdx.x;
    if (e >= E) return;
    int nr = xneis[e];
    if (nr < V) atomicAdd(&count[nr], 1);
}

__global__ __launch_bounds__(256) void scan_block_kernel(
    const int* __restrict__ count, int* __restrict__ scanned, int* __restrict__ blocksum)
{
    __shared__ int s[256];
    int tid = threadIdx.x;
    int i = blockIdx.x * 256 + tid;
    int v = (i < V) ? count[i] : 0;
    s[tid] = v; __syncthreads();
    #pragma unroll
    for (int off = 1; off < 256; off <<= 1) {
        int t = (tid >= off) ? s[tid - off] : 0;
        __syncthreads();
        s[tid] += t;
        __syncthreads();
    }
    if (i < V) scanned[i] = s[tid] - v;          // block-exclusive
    if (tid == 255) blocksum[blockIdx.x] = s[255];
}

__global__ __launch_bounds__(512) void scan_tops_kernel(
    const int* __restrict__ blocksum, int* __restrict__ tops, int* __restrict__ rowptr)
{
    __shared__ int s[512];
    int tid = threadIdx.x;
    int v = (tid < NB) ? blocksum[tid] : 0;
    s[tid] = v; __syncthreads();
    #pragma unroll
    for (int off = 1; off < 512; off <<= 1) {
        int t = (tid >= off) ? s[tid - off] : 0;
        __syncthreads();
        s[tid] += t;
        __syncthreads();
    }
    if (tid < NB) tops[tid] = s[tid] - v;        // exclusive
    if (tid == 511) rowptr[V] = s[511];          // total kept edges
}

__global__ __launch_bounds__(256) void add_offsets_kernel(
    const int* __restrict__ scanned, const int* __restrict__ tops, int* __restrict__ rowptr)
{
    int i = blockIdx.x * 256 + threadIdx.x;
    if (i < V) rowptr[i] = scanned[i] + tops[blockIdx.x];
}

// Packed per-CSR-slot metadata (4 B): src (17 b) | et (4 b) | dg-1 (6 b).
__global__ __launch_bounds__(256) void scatter_kernel(
    const int* __restrict__ xnode, const int* __restrict__ xneis,
    const int* __restrict__ etype, const float* __restrict__ dg,
    const int* __restrict__ rowptr, int* __restrict__ cursor,
    unsigned* __restrict__ meta)
{
    int e = blockIdx.x * 256 + threadIdx.x;
    if (e >= E) return;
    int nr = xneis[e];
    if (nr < V) {
        int p = rowptr[nr] + atomicAdd(&cursor[nr], 1);
        unsigned src = (unsigned)(xnode[e] - 1);
        unsigned et  = (unsigned)(etype[e] - 1);
        unsigned dgi = (unsigned)dg[e] - 1;        // 0..63, exact
        meta[p] = src | (et << 17) | (dgi << 21);
    }
}

// ---------------------------------------------------------------------------
// Per-node bias sum: Bsum[v] = count[v] * tanh(W_rou·feat[v-1]+b)
// ---------------------------------------------------------------------------
__global__ __launch_bounds__(256) void bsum_kernel(
    const float* __restrict__ feat, const int* __restrict__ count,
    const float* __restrict__ Wrou, const float* __restrict__ brou,
    float* __restrict__ Bsum)
{
    __shared__ float Wl[512];
    __shared__ float bl[8];
    int tid = threadIdx.x;
    for (int i = tid; i < 512; i += 256) Wl[i] = Wrou[i];
    if (tid < 8) bl[tid] = brou[tid];
    __syncthreads();

    int v = blockIdx.x * 256 + tid;
    if (v >= V) return;
    int c = count[v];
    float out[8] = {0, 0, 0, 0, 0, 0, 0, 0};
    if (c > 0) {                                  // c>0 implies v >= 1
        const float4* f4 = (const float4*)(feat + (size_t)(v - 1) * 64);
        float acc[8];
        #pragma unroll
        for (int s = 0; s < 8; ++s) acc[s] = bl[s];
        #pragma unroll 4
        for (int k = 0; k < 16; ++k) {
            float4 x = f4[k];
            #pragma unroll
            for (int s = 0; s < 8; ++s) {
                const float* w = &Wl[s * 64 + k * 4];
                acc[s] += x.x * w[0] + x.y * w[1] + x.z * w[2] + x.w * w[3];
            }
        }
        float fc = (float)c;
        #pragma unroll
        for (int s = 0; s < 8; ++s) out[s] = fc * fast_tanh(acc[s]);
    }
    float4* O = (float4*)(Bsum + (size_t)v * 8);
    O[0] = make_float4(out[0], out[1], out[2], out[3]);
    O[1] = make_float4(out[4], out[5], out[6], out[7]);
}

// ---------------------------------------------------------------------------
// PQ GEMM (MFMA): PQ[v][0:64] = feat[v]·Wxi[:, 0:64]^T   (P part)
//                 PQ[v][64:128] = feat[v]·Wxi[:, 64:128]^T (Q part), bf16 out
// ---------------------------------------------------------------------------
__global__ __launch_bounds__(256) void pq_kernel(
    const float* __restrict__ feat, const float* __restrict__ Wxi,
    ushort* __restrict__ PQ)
{
    const int lane = threadIdx.x & 63, wave = threadIdx.x >> 6;
    const int quad = lane >> 4, l16 = lane & 15;

    short8 bP[4][2], bQ[4][2];
    #pragma unroll
    for (int nt = 0; nt < 4; ++nt) {
        #pragma unroll
        for (int ks = 0; ks < 2; ++ks) {
            const float* wp = Wxi + (size_t)(nt * 16 + l16) * KXW + ks * 32 + quad * 8;
            short8 p, q;
            #pragma unroll
            for (int j = 0; j < 8; ++j) { p[j] = f2bf(wp[j]); q[j] = f2bf(wp[64 + j]); }
            bP[nt][ks] = p; bQ[nt][ks] = q;
        }
    }

    int t = blockIdx.x * 4 + wave;
    if (t >= V / 16) return;
    int v0 = t * 16;

    const float* fp = feat + (size_t)(v0 + l16) * 64 + quad * 8;
    short8 a0, a1;
    #pragma unroll
    for (int j = 0; j < 8; ++j) { a0[j] = f2bf(fp[j]); a1[j] = f2bf(fp[32 + j]); }

    float4v accP[4], accQ[4];
    #pragma unroll
    for (int nt = 0; nt < 4; ++nt) {
        float4v z = {0.f, 0.f, 0.f, 0.f};
        z = __builtin_amdgcn_mfma_f32_16x16x32_bf16(a0, bP[nt][0], z, 0, 0, 0);
        z = __builtin_amdgcn_mfma_f32_16x16x32_bf16(a1, bP[nt][1], z, 0, 0, 0);
        accP[nt] = z;
        float4v w = {0.f, 0.f, 0.f, 0.f};
        w = __builtin_amdgcn_mfma_f32_16x16x32_bf16(a0, bQ[nt][0], w, 0, 0, 0);
        w = __builtin_amdgcn_mfma_f32_16x16x32_bf16(a1, bQ[nt][1], w, 0, 0, 0);
        accQ[nt] = w;
    }

    #pragma unroll
    for (int r = 0; r < 4; ++r) {
        ushort* row = PQ + (size_t)(v0 + quad * 4 + r) * 128;
        #pragma unroll
        for (int nt = 0; nt < 4; ++nt) {
            row[nt * 16 + l16]      = (ushort)f2bf(accP[nt][r]);
            row[64 + nt * 16 + l16] = (ushort)f2bf(accQ[nt][r]);
        }
    }
}

// ---------------------------------------------------------------------------
// Fused step, 8 edges in flight per wave: lane = el*8 + s. 32-bit index math.
// When logitsOut != nullptr (last step) the 8 el==0 lanes also fold
// logits[v] = W1·H[v] + b1 via an intra-8-lane shfl tree.
// ---------------------------------------------------------------------------
__global__ __launch_bounds__(256) void step_kernel(
    const float* __restrict__ Hin, float* __restrict__ Hout,
    const unsigned* __restrict__ meta, const int* __restrict__ rowptr,
    const ushort* __restrict__ PQ, const float* __restrict__ Wxi,
    const float* __restrict__ bxi, const float* __restrict__ Bsum,
    const float* __restrict__ W1, const float* __restrict__ b1,
    float* __restrict__ logitsOut)
{
    __shared__ float WetB[NET * 64];
    __shared__ float scT[64];
    int tid = threadIdx.x;
    for (int i = tid; i < NET * 64; i += 256) {
        int et = i >> 6, n = i & 63;
        WetB[i] = Wxi[n * KXW + 128 + et] + bxi[n];
    }
    if (tid < 64) scT[tid] = MUS / (float)(tid + 1);
    __syncthreads();

    int v = blockIdx.x * 4 + (tid >> 6);
    if (v >= V) return;
    int lane = tid & 63;
    int el = lane >> 3, s = lane & 7;

    int p0 = rowptr[v], p1 = rowptr[v + 1];

    // Q components for this lane's row s (constant over the node's edges)
    float q0, q1, q2, q3, q4, q5, q6, q7;
    {
        uint4 qu = *(const uint4*)(PQ + v * 128 + 64 + s * 8);
        q0 = bflo(qu.x); q1 = bfhi(qu.x); q2 = bflo(qu.y); q3 = bfhi(qu.y);
        q4 = bflo(qu.z); q5 = bfhi(qu.z); q6 = bflo(qu.w); q7 = bfhi(qu.w);
    }

    float acc = 0.0f;
    for (int p = p0 + el; p < p1; p += 8) {
        unsigned m = meta[p];
        int src = (int)(m & 0x1FFFF);
        int et  = (int)((m >> 17) & 0xF);
        float sc = scT[m >> 21];

        uint4 pu = *(const uint4*)(PQ + src * 128 + s * 8);
        float4 h0 = *(const float4*)(Hin + src * 8);
        float4 h1 = *(const float4*)(Hin + src * 8 + 4);
        const float4* w4 = (const float4*)(&WetB[et * 64 + s * 8]);
        float4 wa = w4[0], wb = w4[1];

        float d;
        d  = fast_tanh(bflo(pu.x) + q0 + wa.x) * h0.x;
        d += fast_tanh(bfhi(pu.x) + q1 + wa.y) * h0.y;
        d += fast_tanh(bflo(pu.y) + q2 + wa.z) * h0.z;
        d += fast_tanh(bfhi(pu.y) + q3 + wa.w) * h0.w;
        d += fast_tanh(bflo(pu.z) + q4 + wb.x) * h1.x;
        d += fast_tanh(bfhi(pu.z) + q5 + wb.y) * h1.y;
        d += fast_tanh(bflo(pu.w) + q6 + wb.z) * h1.z;
        d += fast_tanh(bfhi(pu.w) + q7 + wb.w) * h1.w;
        acc += sc * d;
    }
    acc += __shfl_xor(acc, 8);            // reduce over edge slots (el bits)
    acc += __shfl_xor(acc, 16);
    acc += __shfl_xor(acc, 32);

    float hfin = acc + Bsum[v * 8 + s];   // valid in all lanes (s preserved)
    if (el == 0)
        Hout[v * 8 + s] = hfin;

    if (logitsOut != nullptr) {
        float t = hfin * W1[s];
        t += __shfl_xor(t, 1);
        t += __shfl_xor(t, 2);
        t += __shfl_xor(t, 4);
        if (lane == 0) logitsOut[v] = t + b1[0];
    }
}

// ---------------------------------------------------------------------------
// Epilogue
// ---------------------------------------------------------------------------
__global__ __launch_bounds__(256) void reduce_max_kernel(
    const float* __restrict__ logits, float* __restrict__ partial)
{
    float m = -INFINITY;
    for (int v = blockIdx.x * 256 + threadIdx.x; v < V; v += 256 * 256)
        m = fmaxf(m, logits[v]);
    #pragma unroll
    for (int o = 32; o > 0; o >>= 1) m = fmaxf(m, __shfl_down(m, o));
    __shared__ float sm[4];
    if ((threadIdx.x & 63) == 0) sm[threadIdx.x >> 6] = m;
    __syncthreads();
    if (threadIdx.x == 0)
        partial[blockIdx.x] = fmaxf(fmaxf(sm[0], sm[1]), fmaxf(sm[2], sm[3]));
}

__global__ __launch_bounds__(256) void final_max_kernel(
    const float* __restrict__ partial, float* __restrict__ M)
{
    float m = partial[threadIdx.x];
    #pragma unroll
    for (int o = 32; o > 0; o >>= 1) m = fmaxf(m, __shfl_down(m, o));
    __shared__ float sm[4];
    if ((threadIdx.x & 63) == 0) sm[threadIdx.x >> 6] = m;
    __syncthreads();
    if (threadIdx.x == 0) *M = fmaxf(fmaxf(sm[0], sm[1]), fmaxf(sm[2], sm[3]));
}

// Stage 1: 64 blocks write per-block partials (9 floats each) — no atomics.
__global__ __launch_bounds__(256) void sum_kernel(
    const float* __restrict__ H, const float* __restrict__ logits,
    const float* __restrict__ Mp, float* __restrict__ partial)
{
    const float M = *Mp;
    float se = 0.0f;
    float sh[8] = {0, 0, 0, 0, 0, 0, 0, 0};
    for (int v = blockIdx.x * 256 + threadIdx.x; v < V; v += 64 * 256) {
        float w = __expf(logits[v] - M);
        se += w;
        const float4* H4 = (const float4*)(H + (size_t)v * 8);
        float4 h0 = H4[0], h1 = H4[1];
        sh[0] += w * h0.x; sh[1] += w * h0.y; sh[2] += w * h0.z; sh[3] += w * h0.w;
        sh[4] += w * h1.x; sh[5] += w * h1.y; sh[6] += w * h1.z; sh[7] += w * h1.w;
    }
    #pragma unroll
    for (int o = 32; o > 0; o >>= 1) {
        se += __shfl_xor(se, o);
        #pragma unroll
        for (int i = 0; i < 8; ++i) sh[i] += __shfl_xor(sh[i], o);
    }
    __shared__ float sm[4][9];
    int wv = threadIdx.x >> 6;
    if ((threadIdx.x & 63) == 0) {
        sm[wv][8] = se;
        #pragma unroll
        for (int i = 0; i < 8; ++i) sm[wv][i] = sh[i];
    }
    __syncthreads();
    if (threadIdx.x == 0) {
        #pragma unroll
        for (int i = 0; i < 9; ++i)
            partial[blockIdx.x * 12 + i] = sm[0][i] + sm[1][i] + sm[2][i] + sm[3][i];
    }
}

// Stage 2: one wave reduces the 64 partials and writes the final 8 outputs.
__global__ void final_kernel(const float* __restrict__ partial, float* __restrict__ out)
{
    int lane = threadIdx.x;               // 64 threads
    float vals[9];
    #pragma unroll
    for (int i = 0; i < 9; ++i) vals[i] = partial[lane * 12 + i];
    #pragma unroll
    for (int o = 1; o < 64; o <<= 1) {
        #pragma unroll
        for (int i = 0; i < 9; ++i) vals[i] += __shfl_xor(vals[i], o);
    }
    __shared__ float res[9];
    if (lane == 0) {
        #pragma unroll
        for (int i = 0; i < 9; ++i) res[i] = vals[i];
    }
    __syncthreads();
    if (lane < 8) out[lane] = tanhf(res[lane] / res[8]);
}

// ---------------------------------------------------------------------------
extern "C" void kernel_launch(void* const* d_in, const int* in_sizes, int n_in,
                              void* d_out, int out_size, void* d_ws, size_t ws_size,
                              hipStream_t stream)
{
    const float* feat  = (const float*)d_in[0];
    const int*   xnode = (const int*)d_in[1];
    const int*   xneis = (const int*)d_in[2];
    const int*   etype = (const int*)d_in[3];
    const float* dg    = (const float*)d_in[4];
    const float* Hinit = (const float*)d_in[5];
    const float* Wxi   = (const float*)d_in[6];
    const float* bxi   = (const float*)d_in[7];
    const float* Wrou  = (const float*)d_in[8];
    const float* brou  = (const float*)d_in[9];
    const float* W1    = (const float*)d_in[10];
    const float* b1    = (const float*)d_in[11];

    char* ws = (char*)d_ws;
    auto alloc = [&](size_t bytes) -> char* {
        char* p = ws; ws += (bytes + 255) & ~(size_t)255; return p;
    };
    // Budget: ~48 MB total
    ushort*   PQ      = (ushort*)alloc((size_t)V * 128 * 2);  // 25.6 MB (bf16)
    unsigned* meta    = (unsigned*)alloc((size_t)E * 4);      // 6.4 MB (packed)
    float*    B0      = (float*)alloc((size_t)V * 8 * 4);     // 3.2 MB
    float*    B1      = (float*)alloc((size_t)V * 8 * 4);     // 3.2 MB
    float*    Bsum    = (float*)alloc((size_t)V * 8 * 4);     // 3.2 MB
    int*      count   = (int*)alloc((size_t)2 * V * 4);       // 0.8 MB (count+cursor)
    int*      cursor  = count + V;
    int*      scanned = (int*)alloc((size_t)V * 4);
    int*      rowptr  = (int*)alloc((size_t)(V + 1) * 4);
    int*      blocksum= (int*)alloc(512 * 4);
    int*      tops    = (int*)alloc(512 * 4);
    float*    logits  = (float*)alloc((size_t)V * 4);
    float*    pmax    = (float*)alloc(256 * 4);
    float*    Mp      = (float*)alloc(16);
    float*    spart   = (float*)alloc(64 * 12 * 4);

    hipMemsetAsync(count, 0, (size_t)2 * V * 4, stream);
    hist_kernel<<<(E + 255) / 256, 256, 0, stream>>>(xneis, count);
    scan_block_kernel<<<NB, 256, 0, stream>>>(count, scanned, blocksum);
    scan_tops_kernel<<<1, 512, 0, stream>>>(blocksum, tops, rowptr);
    add_offsets_kernel<<<NB, 256, 0, stream>>>(scanned, tops, rowptr);
    scatter_kernel<<<(E + 255) / 256, 256, 0, stream>>>(xnode, xneis, etype, dg,
                                                        rowptr, cursor, meta);
    pq_kernel<<<(V / 16 + 3) / 4, 256, 0, stream>>>(feat, Wxi, PQ);
    bsum_kernel<<<NB, 256, 0, stream>>>(feat, count, Wrou, brou, Bsum);

    const float* Hcur = Hinit;
    float* bufs[2] = {B0, B1};
    for (int t = 0; t < 4; ++t) {
        float* Hn = bufs[t & 1];
        float* lg = (t == 3) ? logits : nullptr;
        step_kernel<<<(V + 3) / 4, 256, 0, stream>>>(Hcur, Hn, meta, rowptr,
                                                     PQ, Wxi, bxi, Bsum,
                                                     W1, b1, lg);
        Hcur = Hn;
    }

    reduce_max_kernel<<<256, 256, 0, stream>>>(logits, pmax);
    final_max_kernel<<<1, 256, 0, stream>>>(pmax, Mp);
    sum_kernel<<<64, 256, 0, stream>>>(Hcur, logits, Mp, spart);
    final_kernel<<<1, 64, 0, stream>>>(spart, (float*)d_out);
}